// Round 10
// baseline (93.358 us; speedup 1.0000x reference)
//
#include <hip/hip_runtime.h>
#include <hip/hip_bf16.h>
#include <math.h>

// Shapes: B=32, C=128, O=128, K=3, L=4096, W=1, PAD=1, DIL=1
// Fully fused: one kernel per (128-i tile, b). x read ONCE:
//   pass A: stage 4 x-windows [32c x 160i] fp32 in LDS (pipelined loads).
//   conv:   offset/mask conv as MFMA (A = bf16 conv weights, 16-row padded;
//           B = window reads at integer taps). C-frag -> LDS exchange ->
//           per-lane gather params (addr, wa, wb) in registers.
//   pass B: round-9 producer/consumer: wave w interps i-frag w -> Bl dbuf;
//           consumes as m-frag w with A-frags in registers. One barrier/phase.
//
// ws layout (bytes):
//   WrA @ 0     : bf16 A-frags main GEMM, 8 m x 12 s x 64 lanes x 16B = 98304
//   WcA @ 98304 : bf16 A-frags conv, 12 s x 64 lanes x 16B = 12288

typedef __attribute__((ext_vector_type(8))) short bf16x8;
typedef __attribute__((ext_vector_type(4))) float f32x4;
typedef float f32x2u __attribute__((ext_vector_type(2), aligned(4)));

#define WIN 160
#define WPAD 161

static __device__ inline unsigned short f2bf(float f) {
    __hip_bfloat16 h = __float2bfloat16(f);
    union { __hip_bfloat16 b; unsigned short u; } cv;
    cv.b = h;
    return cv.u;
}

// ---------- kernel 0: pack WrA (main A-frags) + WcA (conv A-frags) ----------
// A-frag (m,s), lane l, elem e:  A[o = m*16+(l&15)][kc = s*32+(l>>4)*8+e]
// kc = k*128 + c  (k = conv tap for both GEMMs)
__global__ __launch_bounds__(256) void k_wra(const float* __restrict__ w_reg,
                                             const float* __restrict__ w_off,
                                             const float* __restrict__ w_mod,
                                             unsigned short* __restrict__ WrA,
                                             unsigned short* __restrict__ WcA) {
    int t = blockIdx.x * 256 + threadIdx.x;
    if (t < 49152) {
        int e  = t & 7;
        int l  = (t >> 3) & 63;
        int ms = t >> 9;              // m*12 + s
        int m  = ms / 12;
        int s  = ms - m * 12;
        int o  = m * 16 + (l & 15);
        int kc = s * 32 + ((l >> 4) & 3) * 8 + e;
        int tap = kc >> 7;
        int c   = kc & 127;
        WrA[t] = f2bf(w_reg[(o * 128 + c) * 3 + tap]);
    } else if (t < 49152 + 6144) {
        int u = t - 49152;
        int e = u & 7;
        int l = (u >> 3) & 63;
        int s = u >> 9;               // 0..11
        int o = l & 15;
        int c   = (s & 3) * 32 + ((l >> 4) & 3) * 8 + e;
        int tap = s >> 2;
        float v = 0.f;
        if (o < 6)      v = w_off[(o * 128 + c) * 3 + tap];
        else if (o < 9) v = w_mod[((o - 6) * 128 + c) * 3 + tap];
        WcA[u] = f2bf(v);
    }
}

// ---------- kernel 1: fully fused conv + gather + GEMM ----------
// grid (32 i-tiles, 32 b), 512 threads = 8 waves.
__global__ __launch_bounds__(512) void k_all(const unsigned short* __restrict__ WrA,
                                             const unsigned short* __restrict__ WcA,
                                             const float* __restrict__ x,
                                             const float* __restrict__ b_off,
                                             const float* __restrict__ b_mod,
                                             float* __restrict__ out) {
    __shared__ float win[4][32 * WPAD];          // 82.4 KB, resident all kernel
    __shared__ short Bl[2][8][3][512];           // 48 KB B-frag double buffer
    float* convx = (float*)&Bl[0][0][0][0];      // [9][132] aliased scratch

    int t = threadIdx.x;
    int l = t & 63;
    int w = t >> 6;                               // 0..7
    int b  = blockIdx.y;
    int ib = blockIdx.x;
    int q  = l >> 4;
    int il = l & 15;
    int i0t = ib * 128;
    int wsod = i0t - 16;
    if (wsod > 4096 - WIN) wsod = 4096 - WIN;
    if (wsod < 0) wsod = 0;
    const float* xb = x + (size_t)b * 524288;
    const bf16x8* Ag = (const bf16x8*)WrA;
    const bf16x8* Ac = (const bf16x8*)WcA;

    // ---- pass A: stage 4 windows, software-pipelined ----
    int  rr_[3], co_[3];
    bool v_[3];
#pragma unroll
    for (int it = 0; it < 3; ++it) {
        int idx = it * 512 + t;                   // 1280 float4-chunks total
        int r = idx / 40;
        rr_[it] = r;
        co_[it] = (idx - r * 40) * 4;             // dword offset in row
        v_[it]  = (idx < 1280);
    }
    float4 sA[3], sB[3];
#define LOADW(dst, cc) \
    _Pragma("unroll") for (int it = 0; it < 3; ++it) if (v_[it]) \
        dst[it] = *(const float4*)(xb + (size_t)((cc) * 32 + rr_[it]) * 4096 + wsod + co_[it]);
#define WRITEW(src, cc) \
    _Pragma("unroll") for (int it = 0; it < 3; ++it) if (v_[it]) { \
        float* d = &win[cc][rr_[it] * WPAD + co_[it]]; \
        d[0] = src[it].x; d[1] = src[it].y; d[2] = src[it].z; d[3] = src[it].w; }

    LOADW(sA, 0) LOADW(sB, 1) WRITEW(sA, 0) LOADW(sA, 2)
    WRITEW(sB, 1) LOADW(sB, 3) WRITEW(sA, 2) WRITEW(sB, 3)
#undef LOADW
#undef WRITEW
    __syncthreads();

    // ---- conv via MFMA: wave w -> i-frag w; C rows = conv channels ----
    int gi = i0t + w * 16 + il;                   // this lane's i (col in frag)
    f32x4 cv = (f32x4){0.f, 0.f, 0.f, 0.f};
#pragma unroll
    for (int s = 0; s < 12; ++s) {
        int tap = s >> 2;
        int wcc = s & 3;
        int gk  = gi + tap - 1;
        bool ok = (gk >= 0) && (gk < 4096);       // conv zero-pad
        int pos = gk - wsod;
        float vv[8];
#pragma unroll
        for (int e = 0; e < 8; ++e)
            vv[e] = ok ? win[wcc][(q * 8 + e) * WPAD + pos] : 0.f;
        bf16x8 Bv;
#pragma unroll
        for (int e = 0; e < 8; ++e) Bv[e] = (short)f2bf(vv[e]);
        cv = __builtin_amdgcn_mfma_f32_16x16x32_bf16(Ac[s * 64 + l], Bv, cv, 0, 0, 0);
    }

    // exchange conv C-frag (rows q*4+rr = channels) -> convx[ch][i_local]
    int ilocal = w * 16 + il;
#pragma unroll
    for (int rr = 0; rr < 4; ++rr) {
        int ch = q * 4 + rr;
        if (ch < 9) convx[ch * 132 + ilocal] = cv[rr];
    }
    __syncthreads();

    float c9[9];
#pragma unroll
    for (int z = 0; z < 9; ++z) c9[z] = convx[z * 132 + ilocal];
    __syncthreads();                              // convx reads before Bl writes

    // ---- gather params for producer role (i = gi) ----
    int   a_[3];
    float wa_[3], wb_[3];
    bool  okw[3];
#pragma unroll
    for (int k = 0; k < 3; ++k) {
        float offy = c9[2 * k]     + b_off[2 * k];
        float offx = c9[2 * k + 1] + b_off[2 * k + 1];
        offy = fminf(fmaxf(offy, -1024.f), 1024.f);
        offx = fminf(fmaxf(offx, -1024.f), 1024.f);
        float am = c9[6 + k] + b_mod[k];
        float m  = 2.f / (1.f + expf(-am));

        float py = (float)(gi - 1 + k) + offy;
        float y0 = floorf(py);
        int   iy0 = (int)y0;
        float wy1 = py - y0, wy0 = 1.f - wy1;
        float x0f = floorf(offx);
        int   ix0 = (int)x0f;
        float wx1 = offx - x0f, wx0 = 1.f - wx1;

        float sx = (ix0 == 0) ? wx0 : ((ix0 == -1) ? wx1 : 0.f);
        float scal = m * sx;

        float wAv = (iy0 >= 0 && iy0 < 4096)  ? scal * wy0 : 0.f;
        float wBv = (iy0 >= -1 && iy0 < 4095) ? scal * wy1 : 0.f;

        int addr = min(max(iy0, 0), 4094);
        bool eq = (iy0 == addr);
        wa_[k] = eq ? wAv : (iy0 == -1   ? wBv : 0.f);
        wb_[k] = eq ? wBv : (iy0 == 4095 ? wAv : 0.f);
        a_[k]  = addr;
        okw[k] = (bool)__all((int)(addr >= wsod && addr <= wsod + WIN - 2));
    }

    // ---- pass B: producer/consumer GEMM (round-9 structure, windows resident) ----
    f32x4 acc[8];
#pragma unroll
    for (int f = 0; f < 8; ++f) acc[f] = (f32x4){0.f, 0.f, 0.f, 0.f};

#pragma unroll
    for (int cc = 0; cc < 4; ++cc) {
        int p  = cc & 1;
        int cb = cc * 32;
        bf16x8 Areg[3];
#pragma unroll
        for (int k = 0; k < 3; ++k)
            Areg[k] = Ag[(w * 12 + k * 4 + cc) * 64 + l];

#pragma unroll
        for (int k = 0; k < 3; ++k) {
            float vv[8];
            float wa = wa_[k], wb = wb_[k];
            if (okw[k]) {
                int pos = a_[k] - wsod;
#pragma unroll
                for (int e = 0; e < 8; ++e) {
                    const float* base = &win[cc][(q * 8 + e) * WPAD + pos];
                    vv[e] = wa * base[0] + wb * base[1];    // ds_read2_b32
                }
            } else {
                int a = a_[k];
#pragma unroll
                for (int e = 0; e < 8; ++e) {
                    const float* row = xb + (size_t)(cb + q * 8 + e) * 4096;
                    f32x2u p2 = *(const f32x2u*)(row + a);
                    vv[e] = wa * p2.x + wb * p2.y;
                }
            }
            bf16x8 Bv;
#pragma unroll
            for (int e = 0; e < 8; ++e) Bv[e] = (short)f2bf(vv[e]);
            *(bf16x8*)&Bl[p][w][k][l * 8] = Bv;
        }
        __syncthreads();                          // Bl[p] ready (also guards p-reuse)

        __builtin_amdgcn_s_setprio(1);
#pragma unroll
        for (int f = 0; f < 8; ++f) {
#pragma unroll
            for (int k = 0; k < 3; ++k) {
                bf16x8 Bv = *(const bf16x8*)&Bl[p][f][k][l * 8];
                acc[f] = __builtin_amdgcn_mfma_f32_16x16x32_bf16(Areg[k], Bv, acc[f], 0, 0, 0);
            }
        }
        __builtin_amdgcn_s_setprio(0);
    }

    // C layout: col = lane&15, row = (lane>>4)*4 + reg. Wave w -> o rows w*16..+15.
    int r0 = q * 4;
#pragma unroll
    for (int f = 0; f < 8; ++f) {
#pragma unroll
        for (int r = 0; r < 4; ++r) {
            int o = w * 16 + r0 + r;
            out[((size_t)(b * 128 + o)) * 4096 + i0t + f * 16 + il] = acc[f][r];
        }
    }
}

extern "C" void kernel_launch(void* const* d_in, const int* in_sizes, int n_in,
                              void* d_out, int out_size, void* d_ws, size_t ws_size,
                              hipStream_t stream) {
    const float* x     = (const float*)d_in[0];
    const float* w_off = (const float*)d_in[1];
    const float* b_off = (const float*)d_in[2];
    const float* w_mod = (const float*)d_in[3];
    const float* b_mod = (const float*)d_in[4];
    const float* w_reg = (const float*)d_in[5];
    float* out = (float*)d_out;

    char* ws = (char*)d_ws;
    unsigned short* WrA = (unsigned short*)(ws);
    unsigned short* WcA = (unsigned short*)(ws + 98304);

    k_wra<<<216, 256, 0, stream>>>(w_reg, w_off, w_mod, WrA, WcA);
    k_all<<<dim3(32, 32), 512, 0, stream>>>(WrA, WcA, x, b_off, b_mod, out);
}

// Round 11
// 78.492 us; speedup vs baseline: 1.1894x; 1.1894x over previous
//
#include <hip/hip_runtime.h>
#include <hip/hip_bf16.h>
#include <math.h>

// Shapes: B=32, C=128, O=128, K=3, L=4096, W=1, PAD=1, DIL=1
// out[b,o,i] = sum_kc Wr[kc,o] * G[b,kc,i],  kc = k*128+c (K=384)
// G[b,kc,i] = wae[b,k,i]*x[b,c,addr] + wbe[b,k,i]*x[b,c,addr+1]
//
// Round-11 = round-9 structure with 4x (not 8x) B-fragment sharing:
// consumer wave w = m-group (w&3, 32 o rows) x i-half (w>>2, 4 i-frags).
// Each Bl frag read by 4 waves -> Bl LDS reads halved (786->393 KB/block).
// Producer (wave w interps i-frag w), staging, barriers: identical to r9.
//
// ws layout (bytes):
//   WrA @ 0       : bf16 A-frags, 8 m x 12 s x 64 lanes x 16B = 98304
//   wT  @ 98304   : float[128*32] transposed conv weights, wT[c*32+ch*3+tap]
//   addr2 @ 131072: int[32*3*4096]
//   wae @ 1703936 : float[32*3*4096]
//   wbe @ 3276800 : float[32*3*4096]

typedef __attribute__((ext_vector_type(8))) short bf16x8;
typedef __attribute__((ext_vector_type(4))) float f32x4;
typedef float f32x2u __attribute__((ext_vector_type(2), aligned(4)));

#define WIN 160
#define WPAD 161

static __device__ inline unsigned short f2bf(float f) {
    __hip_bfloat16 h = __float2bfloat16(f);
    union { __hip_bfloat16 b; unsigned short u; } cv;
    cv.b = h;
    return cv.u;
}

// ---------- kernel 0: pack WrA (A-frags) + wT (transposed conv weights) ----------
// A-frag (m,s), lane l, elem e:  A[o = m*16+(l&15)][kc = s*32+(l>>4)*8+e]
__global__ __launch_bounds__(256) void k_wra(const float* __restrict__ w_reg,
                                             const float* __restrict__ w_off,
                                             const float* __restrict__ w_mod,
                                             unsigned short* __restrict__ WrA,
                                             float* __restrict__ wT) {
    int t = blockIdx.x * 256 + threadIdx.x;
    if (t < 8 * 12 * 64 * 8) {
        int e  = t & 7;
        int l  = (t >> 3) & 63;
        int ms = t >> 9;              // m*12 + s
        int m  = ms / 12;
        int s  = ms - m * 12;
        int o  = m * 16 + (l & 15);
        int kc = s * 32 + ((l >> 4) & 3) * 8 + e;
        int tap = kc >> 7;
        int c   = kc & 127;
        WrA[t] = f2bf(w_reg[(o * 128 + c) * 3 + tap]);
    } else if (t < 8 * 12 * 64 * 8 + 128 * 27) {
        int u = t - 8 * 12 * 64 * 8;
        int c = u / 27, r = u - c * 27;
        int ch = r / 3, tap = r - ch * 3;
        wT[c * 32 + r] = (ch < 6) ? w_off[(ch * 128 + c) * 3 + tap]
                                  : w_mod[((ch - 6) * 128 + c) * 3 + tap];
    }
}

// ---------- kernel 1: offset/mask conv, 8 waves x 16 channels ----------
// grid (32, 32): 128-i tiles, lane owns i,i+1. Wave wv sums c in [16wv,16wv+16).
__global__ __launch_bounds__(512) void k_prep(const float* __restrict__ x,
                                              const float* __restrict__ wT,
                                              const float* __restrict__ b_off,
                                              const float* __restrict__ b_mod,
                                              int* __restrict__ addr2,
                                              float* __restrict__ wae,
                                              float* __restrict__ wbe) {
    __shared__ float red[7 * 64 * 19];            // 34 KB, stride 19 (odd)
    int t = threadIdx.x;
    int lane = t & 63;
    int wv = t >> 6;                              // 0..7
    int b = blockIdx.y;
    int i = blockIdx.x * 128 + lane * 2;          // lane covers i, i+1

    int c0 = __builtin_amdgcn_readfirstlane(wv) * 16;

    float acc[18];
#pragma unroll
    for (int z = 0; z < 18; ++z) acc[z] = 0.f;

    const float* xr = x + (size_t)b * 524288 + (size_t)c0 * 4096;
    const float* wbase = wT + c0 * 32;
#pragma unroll 2
    for (int c = 0; c < 16; ++c) {
        const float* row = xr + (size_t)c * 4096;
        f32x2u v = *(const f32x2u*)(row + i);
        float lm = row[max(i - 1, 0)];            // unconditional, no divergence
        float rp = row[min(i + 2, 4095)];
        float left  = (i > 0)        ? lm : 0.f;
        float right = (i + 2 < 4096) ? rp : 0.f;
        const float* wrow = wbase + c * 32;       // wave-uniform -> s_load
#pragma unroll
        for (int ch = 0; ch < 9; ++ch) {
            float w0 = wrow[ch * 3 + 0];
            float w1 = wrow[ch * 3 + 1];
            float w2 = wrow[ch * 3 + 2];
            acc[ch * 2 + 0] += left * w0 + v.x * w1 + v.y  * w2;
            acc[ch * 2 + 1] += v.x  * w0 + v.y * w1 + right * w2;
        }
    }

    if (wv > 0) {
        float* r = &red[((wv - 1) * 64 + lane) * 19];
#pragma unroll
        for (int z = 0; z < 18; ++z) r[z] = acc[z];
    }
    __syncthreads();
    if (wv != 0) return;

#pragma unroll
    for (int p = 0; p < 7; ++p) {
        const float* r = &red[(p * 64 + lane) * 19];
#pragma unroll
        for (int z = 0; z < 18; ++z) acc[z] += r[z];
    }

#pragma unroll
    for (int k = 0; k < 3; ++k) {
        int   av[2];
        float wav[2], wbv[2];
#pragma unroll
        for (int ii = 0; ii < 2; ++ii) {
            float offy = acc[(2 * k) * 2 + ii]     + b_off[2 * k];
            float offx = acc[(2 * k + 1) * 2 + ii] + b_off[2 * k + 1];
            offy = fminf(fmaxf(offy, -1024.f), 1024.f);
            offx = fminf(fmaxf(offx, -1024.f), 1024.f);
            float am = acc[(6 + k) * 2 + ii] + b_mod[k];
            float m  = 2.f / (1.f + expf(-am));

            float py = (float)(i + ii - 1 + k) + offy;
            float y0 = floorf(py);
            int   iy0 = (int)y0;
            float wy1 = py - y0, wy0 = 1.f - wy1;
            float x0f = floorf(offx);
            int   ix0 = (int)x0f;
            float wx1 = offx - x0f, wx0 = 1.f - wx1;

            float sx = (ix0 == 0) ? wx0 : ((ix0 == -1) ? wx1 : 0.f);
            float scal = m * sx;

            float wAv = (iy0 >= 0 && iy0 < 4096)  ? scal * wy0 : 0.f;
            float wBv = (iy0 >= -1 && iy0 < 4095) ? scal * wy1 : 0.f;

            int addr = min(max(iy0, 0), 4094);
            bool eq = (iy0 == addr);
            wav[ii] = eq ? wAv : (iy0 == -1   ? wBv : 0.f);
            wbv[ii] = eq ? wBv : (iy0 == 4095 ? wAv : 0.f);
            av[ii] = addr;
        }
        int j = (b * 3 + k) * 4096 + i;
        *(int2*)(addr2 + j)  = make_int2(av[0], av[1]);
        *(f32x2u*)(wae + j)  = (f32x2u){wav[0], wav[1]};
        *(f32x2u*)(wbe + j)  = (f32x2u){wbv[0], wbv[1]};
    }
}

// ---------- kernel 2: fused gather + MFMA GEMM, producer/consumer ----------
// grid (32 i-tiles, 32 b), 512 threads = 8 waves. Block: 128 i x 128 o.
// Producer: wave w interps i-frag w -> Bl[p][w][k].
// Consumer: wave w = m-group (w&3: m-frags 2mg,2mg+1) x i-half (w>>2: 4 frags).
__global__ __launch_bounds__(512) void k_fused(const unsigned short* __restrict__ WrA,
                                               const float* __restrict__ x,
                                               const int* __restrict__ addr2,
                                               const float* __restrict__ wae,
                                               const float* __restrict__ wbe,
                                               float* __restrict__ out) {
    __shared__ float win[32 * WPAD];               // 20.6 KB
    __shared__ short Bl[2][8][3][512];             // 2 x 24 KB B-frags
    int t = threadIdx.x;
    int l = t & 63;
    int w = t >> 6;                                // 0..7
    int b  = blockIdx.y;
    int ib = blockIdx.x;
    int q = l >> 4;
    int il = l & 15;
    int mg = w & 3;                                // consumer m-group
    int hh = w >> 2;                               // consumer i-half
    int i0t = ib * 128;
    int i0p = i0t + w * 16 + il;                   // producer's i
    int wsod = i0t - 16;
    if (wsod > 4096 - WIN) wsod = 4096 - WIN;
    if (wsod < 0) wsod = 0;
    const float* xb = x + (size_t)b * 524288;
    const bf16x8* Ag = (const bf16x8*)WrA;

    // producer gather params (own i-frag) + wave-uniform in-window flags
    int   a_[3];
    float wa_[3], wb_[3];
    bool  okw[3];
#pragma unroll
    for (int k = 0; k < 3; ++k) {
        int j = (b * 3 + k) * 4096 + i0p;
        int a = addr2[j];
        a_[k]  = a;
        wa_[k] = wae[j];
        wb_[k] = wbe[j];
        okw[k] = (bool)__all(a >= wsod && a <= wsod + WIN - 2);
    }

    f32x4 acc[2][4];
#pragma unroll
    for (int mm = 0; mm < 2; ++mm)
#pragma unroll
        for (int ff = 0; ff < 4; ++ff) acc[mm][ff] = (f32x4){0.f, 0.f, 0.f, 0.f};

    // prologue: stage window for cc=0
#pragma unroll
    for (int it = 0; it < 3; ++it) {
        int idx = it * 512 + t;
        if (idx < 1280) {
            int r  = idx / 40;
            int cp = idx - r * 40;
            float4 v = *(const float4*)(xb + (size_t)r * 4096 + wsod + cp * 4);
            float* dst = &win[r * WPAD + cp * 4];
            dst[0] = v.x; dst[1] = v.y; dst[2] = v.z; dst[3] = v.w;
        }
    }
    __syncthreads();

    for (int cc = 0; cc < 4; ++cc) {
        int p  = cc & 1;
        int cb = cc * 32;

        // --- consumer A-frags first (oldest vmcnt; stg stays in flight) ---
        bf16x8 Areg[2][3];
#pragma unroll
        for (int mm = 0; mm < 2; ++mm)
#pragma unroll
            for (int k = 0; k < 3; ++k)
                Areg[mm][k] = Ag[((mg * 2 + mm) * 12 + k * 4 + cc) * 64 + l];

        // --- producer: interp own i-frag -> B LDS ---
#pragma unroll
        for (int k = 0; k < 3; ++k) {
            float v[8];
            float wa = wa_[k], wb = wb_[k];
            if (okw[k]) {
                int pos = a_[k] - wsod;
#pragma unroll
                for (int e = 0; e < 8; ++e) {
                    const float* base = &win[(q * 8 + e) * WPAD + pos];
                    v[e] = wa * base[0] + wb * base[1];   // ds_read2_b32
                }
            } else {
                int a = a_[k];
#pragma unroll
                for (int e = 0; e < 8; ++e) {
                    const float* row = xb + (size_t)(cb + q * 8 + e) * 4096;
                    f32x2u p2 = *(const f32x2u*)(row + a);
                    v[e] = wa * p2.x + wb * p2.y;
                }
            }
            bf16x8 Bv;
#pragma unroll
            for (int e = 0; e < 8; ++e) Bv[e] = (short)f2bf(v[e]);
            *(bf16x8*)&Bl[p][w][k][l * 8] = Bv;
        }

        // --- issue next window's loads (T14; consumer section has no VMEM) ---
        float4 stg[3];
        if (cc < 3) {
            const float* src = xb + (size_t)(cb + 32) * 4096;
#pragma unroll
            for (int it = 0; it < 3; ++it) {
                int idx = it * 512 + t;
                if (idx < 1280) {
                    int r  = idx / 40;
                    int cp = idx - r * 40;
                    stg[it] = *(const float4*)(src + (size_t)r * 4096 + wsod + cp * 4);
                }
            }
        }
        __syncthreads();                            // B[p] ready; win reads done

        // --- consumer: pure LDS + MFMA (stage loads in flight underneath) ---
        __builtin_amdgcn_s_setprio(1);
#pragma unroll
        for (int ff = 0; ff < 4; ++ff) {
            int f = hh * 4 + ff;
#pragma unroll
            for (int k = 0; k < 3; ++k) {
                bf16x8 Bv = *(const bf16x8*)&Bl[p][f][k][l * 8];
                acc[0][ff] = __builtin_amdgcn_mfma_f32_16x16x32_bf16(Areg[0][k], Bv, acc[0][ff], 0, 0, 0);
                acc[1][ff] = __builtin_amdgcn_mfma_f32_16x16x32_bf16(Areg[1][k], Bv, acc[1][ff], 0, 0, 0);
            }
        }
        __builtin_amdgcn_s_setprio(0);

        // --- write staged window, one barrier closes the phase ---
        if (cc < 3) {
#pragma unroll
            for (int it = 0; it < 3; ++it) {
                int idx = it * 512 + t;
                if (idx < 1280) {
                    int r  = idx / 40;
                    int cp = idx - r * 40;
                    float* dst = &win[r * WPAD + cp * 4];
                    dst[0] = stg[it].x; dst[1] = stg[it].y;
                    dst[2] = stg[it].z; dst[3] = stg[it].w;
                }
            }
            __syncthreads();
        }
    }

    // C layout: col = lane&15, row = (lane>>4)*4 + reg.
    // Consumer wave w -> o rows mg*32..+32, i cols i0t + hh*64..+64.
    int r0 = q * 4;
#pragma unroll
    for (int mm = 0; mm < 2; ++mm) {
#pragma unroll
        for (int ff = 0; ff < 4; ++ff) {
#pragma unroll
            for (int r = 0; r < 4; ++r) {
                int o = (mg * 2 + mm) * 16 + r0 + r;
                out[((size_t)(b * 128 + o)) * 4096 + i0t + (hh * 4 + ff) * 16 + il] = acc[mm][ff][r];
            }
        }
    }
}

extern "C" void kernel_launch(void* const* d_in, const int* in_sizes, int n_in,
                              void* d_out, int out_size, void* d_ws, size_t ws_size,
                              hipStream_t stream) {
    const float* x     = (const float*)d_in[0];
    const float* w_off = (const float*)d_in[1];
    const float* b_off = (const float*)d_in[2];
    const float* w_mod = (const float*)d_in[3];
    const float* b_mod = (const float*)d_in[4];
    const float* w_reg = (const float*)d_in[5];
    float* out = (float*)d_out;

    char* ws = (char*)d_ws;
    unsigned short* WrA = (unsigned short*)(ws);
    float* wT    = (float*)(ws + 98304);
    int*   addr2 = (int*)  (ws + 131072);
    float* wae   = (float*)(ws + 1703936);
    float* wbe   = (float*)(ws + 3276800);

    k_wra<<<206, 256, 0, stream>>>(w_reg, w_off, w_mod, WrA, wT);
    k_prep<<<dim3(32, 32), 512, 0, stream>>>(x, wT, b_off, b_mod,
                                             addr2, wae, wbe);
    k_fused<<<dim3(32, 32), 512, 0, stream>>>(WrA, x, addr2, wae, wbe, out);
}

// Round 12
// 69.671 us; speedup vs baseline: 1.3400x; 1.1266x over previous
//
#include <hip/hip_runtime.h>
#include <hip/hip_bf16.h>
#include <math.h>

// Shapes: B=32, C=128, O=128, K=3, L=4096, W=1, PAD=1, DIL=1
// out[b,o,i] = sum_kc Wr[kc,o] * G[b,kc,i],  kc = k*128+c (K=384)
// G[b,kc,i] = wae[b,k,i]*x[b,c,addr] + wbe[b,k,i]*x[b,c,addr+1]
//
// r12: k_prep replaced by MFMA conv (k_prepm, r10's verified conv-GEMM with
// per-phase window staging); k_fused = r9 consumer + SINGLE-buffered Bl
// (45 KB LDS -> 3 blocks/CU for barrier-drain overlap).
//
// ws layout (bytes):
//   WrA @ 0       : bf16 A-frags main GEMM, 8m x 12s x 64 x 16B = 98304
//   WcA @ 98304   : bf16 A-frags conv, 12s x 64 x 16B = 12288
//   addr2 @ 131072: int[32*3*4096]
//   wae @ 1703936 : float[32*3*4096]
//   wbe @ 3276800 : float[32*3*4096]

typedef __attribute__((ext_vector_type(8))) short bf16x8;
typedef __attribute__((ext_vector_type(4))) float f32x4;
typedef float f32x2u __attribute__((ext_vector_type(2), aligned(4)));

#define WIN 160
#define WPAD 161

static __device__ inline unsigned short f2bf(float f) {
    __hip_bfloat16 h = __float2bfloat16(f);
    union { __hip_bfloat16 b; unsigned short u; } cv;
    cv.b = h;
    return cv.u;
}

// ---------- kernel 0: pack WrA (main A-frags) + WcA (conv A-frags) ----------
// A-frag (m,s), lane l, elem e:  A[o = m*16+(l&15)][kc = s*32+(l>>4)*8+e]
// kc = tap*128 + c  (s = tap*4 + cblock for conv)
__global__ __launch_bounds__(256) void k_wra(const float* __restrict__ w_reg,
                                             const float* __restrict__ w_off,
                                             const float* __restrict__ w_mod,
                                             unsigned short* __restrict__ WrA,
                                             unsigned short* __restrict__ WcA) {
    int t = blockIdx.x * 256 + threadIdx.x;
    if (t < 49152) {
        int e  = t & 7;
        int l  = (t >> 3) & 63;
        int ms = t >> 9;              // m*12 + s
        int m  = ms / 12;
        int s  = ms - m * 12;
        int o  = m * 16 + (l & 15);
        int kc = s * 32 + ((l >> 4) & 3) * 8 + e;
        int tap = kc >> 7;
        int c   = kc & 127;
        WrA[t] = f2bf(w_reg[(o * 128 + c) * 3 + tap]);
    } else if (t < 49152 + 6144) {
        int u = t - 49152;
        int e = u & 7;
        int l = (u >> 3) & 63;
        int s = u >> 9;               // 0..11 = tap*4 + cblock
        int o = l & 15;
        int c   = (s & 3) * 32 + ((l >> 4) & 3) * 8 + e;
        int tap = s >> 2;
        float v = 0.f;
        if (o < 6)      v = w_off[(o * 128 + c) * 3 + tap];
        else if (o < 9) v = w_mod[((o - 6) * 128 + c) * 3 + tap];
        WcA[u] = f2bf(v);
    }
}

// ---------- kernel 1: conv via MFMA + gather-param precompute ----------
// grid (32 i-tiles, 32 b), 512 thr = 8 waves; wave w owns i-frag w.
__global__ __launch_bounds__(512) void k_prepm(const unsigned short* __restrict__ WcA,
                                               const float* __restrict__ x,
                                               const float* __restrict__ b_off,
                                               const float* __restrict__ b_mod,
                                               int* __restrict__ addr2,
                                               float* __restrict__ wae,
                                               float* __restrict__ wbe) {
    __shared__ float win[32 * WPAD];              // 20.6 KB
    __shared__ float convx[9 * 132];              // 4.8 KB
    int t = threadIdx.x;
    int l = t & 63;
    int w = t >> 6;
    int b  = blockIdx.y;
    int ib = blockIdx.x;
    int q  = l >> 4;
    int il = l & 15;
    int i0t = ib * 128;
    int wsod = i0t - 16;
    if (wsod > 4096 - WIN) wsod = 4096 - WIN;
    if (wsod < 0) wsod = 0;
    const float* xb = x + (size_t)b * 524288;
    const bf16x8* Ac = (const bf16x8*)WcA;
    int gi = i0t + w * 16 + il;

    f32x4 cv = (f32x4){0.f, 0.f, 0.f, 0.f};

    for (int cc = 0; cc < 4; ++cc) {
        int cb = cc * 32;
        __syncthreads();                          // win free to overwrite
#pragma unroll
        for (int it = 0; it < 3; ++it) {
            int idx = it * 512 + t;
            if (idx < 1280) {
                int r  = idx / 40;
                int cp = idx - r * 40;
                float4 v = *(const float4*)(xb + (size_t)(cb + r) * 4096 + wsod + cp * 4);
                float* dst = &win[r * WPAD + cp * 4];
                dst[0] = v.x; dst[1] = v.y; dst[2] = v.z; dst[3] = v.w;
            }
        }
        __syncthreads();

#pragma unroll
        for (int tap = 0; tap < 3; ++tap) {
            int s  = tap * 4 + cc;
            int gk = gi + tap - 1;
            bool ok = (gk >= 0) && (gk < 4096);   // conv zero-pad
            int pos = gk - wsod;
            float vv[8];
#pragma unroll
            for (int e = 0; e < 8; ++e)
                vv[e] = ok ? win[(q * 8 + e) * WPAD + pos] : 0.f;
            bf16x8 Bv;
#pragma unroll
            for (int e = 0; e < 8; ++e) Bv[e] = (short)f2bf(vv[e]);
            cv = __builtin_amdgcn_mfma_f32_16x16x32_bf16(Ac[s * 64 + l], Bv, cv, 0, 0, 0);
        }
    }

    // exchange conv C-frag (rows q*4+rr = channels) -> convx[ch][i_local]
    int ilocal = w * 16 + il;
#pragma unroll
    for (int rr = 0; rr < 4; ++rr) {
        int ch = q * 4 + rr;
        if (ch < 9) convx[ch * 132 + ilocal] = cv[rr];
    }
    __syncthreads();

    if (q != 0) return;                           // one param-writer per i
    float c9[9];
#pragma unroll
    for (int z = 0; z < 9; ++z) c9[z] = convx[z * 132 + ilocal];

#pragma unroll
    for (int k = 0; k < 3; ++k) {
        float offy = c9[2 * k]     + b_off[2 * k];
        float offx = c9[2 * k + 1] + b_off[2 * k + 1];
        offy = fminf(fmaxf(offy, -1024.f), 1024.f);
        offx = fminf(fmaxf(offx, -1024.f), 1024.f);
        float am = c9[6 + k] + b_mod[k];
        float m  = 2.f / (1.f + expf(-am));

        float py = (float)(gi - 1 + k) + offy;
        float y0 = floorf(py);
        int   iy0 = (int)y0;
        float wy1 = py - y0, wy0 = 1.f - wy1;
        float x0f = floorf(offx);
        int   ix0 = (int)x0f;
        float wx1 = offx - x0f, wx0 = 1.f - wx1;

        float sx = (ix0 == 0) ? wx0 : ((ix0 == -1) ? wx1 : 0.f);
        float scal = m * sx;

        float wAv = (iy0 >= 0 && iy0 < 4096)  ? scal * wy0 : 0.f;
        float wBv = (iy0 >= -1 && iy0 < 4095) ? scal * wy1 : 0.f;

        int addr = min(max(iy0, 0), 4094);
        bool eq = (iy0 == addr);
        float wa = eq ? wAv : (iy0 == -1   ? wBv : 0.f);
        float wb = eq ? wBv : (iy0 == 4095 ? wAv : 0.f);

        int j = (b * 3 + k) * 4096 + gi;
        addr2[j] = addr;
        wae[j] = wa;
        wbe[j] = wb;
    }
}

// ---------- kernel 2: fused gather + MFMA GEMM, producer/consumer ----------
// grid (32 i-tiles, 32 b), 512 threads = 8 waves. Block: 128 i x 128 o.
// Producer: wave w interps i-frag w -> Bl[w][k] (single-buffered: the
// producer-write -> barrier -> consumer-read -> barrier schedule already
// orders reuse). Consumer: wave w = m-frag w, A-frags in registers.
__global__ __launch_bounds__(512) void k_fused(const unsigned short* __restrict__ WrA,
                                               const float* __restrict__ x,
                                               const int* __restrict__ addr2,
                                               const float* __restrict__ wae,
                                               const float* __restrict__ wbe,
                                               float* __restrict__ out) {
    __shared__ float win[32 * WPAD];               // 20.6 KB
    __shared__ short Bl[8][3][512];                // 24 KB single buffer
    int t = threadIdx.x;
    int l = t & 63;
    int w = t >> 6;                                // 0..7
    int b  = blockIdx.y;
    int ib = blockIdx.x;
    int q = l >> 4;
    int il = l & 15;
    int i0t = ib * 128;
    int i0p = i0t + w * 16 + il;                   // producer's i
    int wsod = i0t - 16;
    if (wsod > 4096 - WIN) wsod = 4096 - WIN;
    if (wsod < 0) wsod = 0;
    const float* xb = x + (size_t)b * 524288;
    const bf16x8* Ag = (const bf16x8*)WrA;

    // producer gather params (own i-frag) + wave-uniform in-window flags
    int   a_[3];
    float wa_[3], wb_[3];
    bool  okw[3];
#pragma unroll
    for (int k = 0; k < 3; ++k) {
        int j = (b * 3 + k) * 4096 + i0p;
        int a = addr2[j];
        a_[k]  = a;
        wa_[k] = wae[j];
        wb_[k] = wbe[j];
        okw[k] = (bool)__all(a >= wsod && a <= wsod + WIN - 2);
    }

    f32x4 acc[8];
#pragma unroll
    for (int f = 0; f < 8; ++f) acc[f] = (f32x4){0.f, 0.f, 0.f, 0.f};

    // prologue: stage window for cc=0
#pragma unroll
    for (int it = 0; it < 3; ++it) {
        int idx = it * 512 + t;
        if (idx < 1280) {
            int r  = idx / 40;
            int cp = idx - r * 40;
            float4 v = *(const float4*)(xb + (size_t)r * 4096 + wsod + cp * 4);
            float* dst = &win[r * WPAD + cp * 4];
            dst[0] = v.x; dst[1] = v.y; dst[2] = v.z; dst[3] = v.w;
        }
    }
    __syncthreads();

    for (int cc = 0; cc < 4; ++cc) {
        int cb = cc * 32;

        // consumer A-frags first (oldest vmcnt; stg stays behind them)
        bf16x8 Areg[3];
#pragma unroll
        for (int k = 0; k < 3; ++k)
            Areg[k] = Ag[(w * 12 + k * 4 + cc) * 64 + l];

        // --- producer: interp own i-frag -> B LDS ---
#pragma unroll
        for (int k = 0; k < 3; ++k) {
            float v[8];
            float wa = wa_[k], wb = wb_[k];
            if (okw[k]) {
                int pos = a_[k] - wsod;
#pragma unroll
                for (int e = 0; e < 8; ++e) {
                    const float* base = &win[(q * 8 + e) * WPAD + pos];
                    v[e] = wa * base[0] + wb * base[1];   // ds_read2_b32
                }
            } else {
                int a = a_[k];
#pragma unroll
                for (int e = 0; e < 8; ++e) {
                    const float* row = xb + (size_t)(cb + q * 8 + e) * 4096;
                    f32x2u p2 = *(const f32x2u*)(row + a);
                    v[e] = wa * p2.x + wb * p2.y;
                }
            }
            bf16x8 Bv;
#pragma unroll
            for (int e = 0; e < 8; ++e) Bv[e] = (short)f2bf(v[e]);
            *(bf16x8*)&Bl[w][k][l * 8] = Bv;
        }

        // --- issue next window's loads (T14; consumer section has no VMEM) ---
        float4 stg[3];
        if (cc < 3) {
            const float* src = xb + (size_t)(cb + 32) * 4096;
#pragma unroll
            for (int it = 0; it < 3; ++it) {
                int idx = it * 512 + t;
                if (idx < 1280) {
                    int r  = idx / 40;
                    int cp = idx - r * 40;
                    stg[it] = *(const float4*)(src + (size_t)r * 4096 + wsod + cp * 4);
                }
            }
        }
        __syncthreads();                            // Bl ready; win reads done

        // --- consumer: pure LDS + MFMA ---
        __builtin_amdgcn_s_setprio(1);
#pragma unroll
        for (int f = 0; f < 8; ++f) {
#pragma unroll
            for (int k = 0; k < 3; ++k) {
                bf16x8 Bv = *(const bf16x8*)&Bl[f][k][l * 8];
                acc[f] = __builtin_amdgcn_mfma_f32_16x16x32_bf16(Areg[k], Bv, acc[f], 0, 0, 0);
            }
        }
        __builtin_amdgcn_s_setprio(0);

        // --- write staged window; barrier closes phase (orders Bl reuse too) ---
        if (cc < 3) {
#pragma unroll
            for (int it = 0; it < 3; ++it) {
                int idx = it * 512 + t;
                if (idx < 1280) {
                    int r  = idx / 40;
                    int cp = idx - r * 40;
                    float* dst = &win[r * WPAD + cp * 4];
                    dst[0] = stg[it].x; dst[1] = stg[it].y;
                    dst[2] = stg[it].z; dst[3] = stg[it].w;
                }
            }
            __syncthreads();
        }
    }

    // C layout: col = lane&15, row = (lane>>4)*4 + reg. Wave w -> o rows w*16..+15.
    int r0 = q * 4;
#pragma unroll
    for (int f = 0; f < 8; ++f) {
#pragma unroll
        for (int r = 0; r < 4; ++r) {
            int o = w * 16 + r0 + r;
            out[((size_t)(b * 128 + o)) * 4096 + i0t + f * 16 + il] = acc[f][r];
        }
    }
}

extern "C" void kernel_launch(void* const* d_in, const int* in_sizes, int n_in,
                              void* d_out, int out_size, void* d_ws, size_t ws_size,
                              hipStream_t stream) {
    const float* x     = (const float*)d_in[0];
    const float* w_off = (const float*)d_in[1];
    const float* b_off = (const float*)d_in[2];
    const float* w_mod = (const float*)d_in[3];
    const float* b_mod = (const float*)d_in[4];
    const float* w_reg = (const float*)d_in[5];
    float* out = (float*)d_out;

    char* ws = (char*)d_ws;
    unsigned short* WrA = (unsigned short*)(ws);
    unsigned short* WcA = (unsigned short*)(ws + 98304);
    int*   addr2 = (int*)  (ws + 131072);
    float* wae   = (float*)(ws + 1703936);
    float* wbe   = (float*)(ws + 3276800);

    k_wra<<<216, 256, 0, stream>>>(w_reg, w_off, w_mod, WrA, WcA);
    k_prepm<<<dim3(32, 32), 512, 0, stream>>>(WcA, x, b_off, b_mod,
                                              addr2, wae, wbe);
    k_fused<<<dim3(32, 32), 512, 0, stream>>>(WrA, x, addr2, wae, wbe, out);
}